// Round 5
// baseline (256.403 us; speedup 1.0000x reference)
//
#include <hip/hip_runtime.h>
#include <cstdint>
#include <cstddef>

typedef unsigned short u16;
typedef __attribute__((ext_vector_type(8))) short sh8;       // 8 x 16-bit (4 VGPR)
typedef __attribute__((ext_vector_type(8))) _Float16 hf8;    // 8 fp16 (4 VGPR)
typedef __attribute__((ext_vector_type(4))) float f4;        // 4 f32

#define MFMA16B(a, b, c) __builtin_amdgcn_mfma_f32_16x16x32_bf16((a), (b), (c), 0, 0, 0)
#define MFMA16H(a, b, c) __builtin_amdgcn_mfma_f32_16x16x32_f16((a), (b), (c), 0, 0, 0)

__device__ __forceinline__ u16 f2bf(float f) {
  union { float f; uint32_t u; } v; v.f = f;
  uint32_t u = v.u;
  uint32_t lsb = (u >> 16) & 1u;
  return (u16)((u + 0x7fffu + lsb) >> 16);   // RNE
}
__device__ __forceinline__ float bf2f(u16 h) {
  union { uint32_t u; float f; } v; v.u = ((uint32_t)h) << 16;
  return v.f;
}

// async global->LDS, 16B per lane. LDS dest must be linear in lane order.
__device__ __forceinline__ void aload16(const void* g, void* l) {
  __builtin_amdgcn_global_load_lds(
      (const __attribute__((address_space(1))) uint32_t*)g,
      (__attribute__((address_space(3))) uint32_t*)l, 16, 0, 0);
}

__device__ __forceinline__ void pbar() {            // phase barrier (no drain)
  __builtin_amdgcn_sched_barrier(0);
  __builtin_amdgcn_s_barrier();
  __builtin_amdgcn_sched_barrier(0);
}

// 12 MFMAs for one quadrant; MH/NH must be literal constants.
#define QUAD12(Af, Bf, MH, NH)                                                \
  {                                                                           \
    __builtin_amdgcn_s_setprio(1);                                            \
    _Pragma("unroll") for (int kk = 0; kk < 2; ++kk)                          \
      _Pragma("unroll") for (int nf = 0; nf < 2; ++nf)                        \
        _Pragma("unroll") for (int mf = 0; mf < 3; ++mf)                      \
          acc[(MH)*3 + mf][(NH)*2 + nf] = MFMA16H(                            \
              Af[mf][kk], Bf[nf][kk], acc[(MH)*3 + mf][(NH)*2 + nf]);         \
    __builtin_amdgcn_s_setprio(0);                                            \
  }

// ---------------------------------------------------------------------------
// Kernel 1: split fp32 weights into 2 fp16 planes.
// qkv layout: [1536][1024] rows = (q|k|v), cols 0-511 = h0, 512-1023 = h1.
// proj layout: [sp][512][512].
// ---------------------------------------------------------------------------
__global__ void prep_weights(const float* __restrict__ qw, const float* __restrict__ kw,
                             const float* __restrict__ vw, const float* __restrict__ pw,
                             u16* __restrict__ w2qkv, u16* __restrict__ w2p) {
  #pragma clang fp contract(off)
  int row = blockIdx.x;  // 0..2047
  for (int c = threadIdx.x; c < 512; c += 256) {
    const float* src;
    if (row < 1536) {
      int br = row >> 9;
      src = (br == 0 ? qw : (br == 1 ? kw : vw)) + (size_t)(row & 511) * 512;
    } else {
      src = pw + (size_t)(row - 1536) * 512;
    }
    float w = src[c];
    _Float16 h0 = (_Float16)w;
    float r1 = w - (float)h0;
    _Float16 h1 = (_Float16)r1;
    union { _Float16 h; u16 u; } u0, u1;
    u0.h = h0; u1.h = h1;
    if (row < 1536) {
      w2qkv[(size_t)row * 1024 + c] = u0.u;
      w2qkv[(size_t)row * 1024 + 512 + c] = u1.u;
    } else {
      int m = row - 1536;
      w2p[(size_t)m * 512 + c] = u0.u;
      w2p[(size_t)(512 + m) * 512 + c] = u1.u;
    }
  }
}

__global__ void bn_prep(const float* __restrict__ g, const float* __restrict__ be,
                        const float* __restrict__ mu, const float* __restrict__ va,
                        float* __restrict__ inv, float* __restrict__ add) {
  #pragma clang fp contract(off)
  int i = blockIdx.x * 256 + threadIdx.x;
  if (i < 512) {
    float iv = g[i] / sqrtf(va[i] + 1e-5f);
    inv[i] = iv;
    add[i] = be[i] - mu[i] * iv;
  }
}

// ---------------------------------------------------------------------------
// Kernel 2: LIF over x -> spikes, stored TRANSPOSED sT[t][b][n][c] (fp16: 0x3C00).
// ---------------------------------------------------------------------------
__global__ __launch_bounds__(256) void lif0(const float* __restrict__ x, u16* __restrict__ sT) {
  #pragma clang fp contract(off)
  __shared__ u16 st[64 * 80];   // [n][c] padded
  const int tid = threadIdx.x;
  const int n0 = blockIdx.x * 64;
  const int c0 = blockIdx.y * 64;
  const int b = blockIdx.z;
  const int cl = tid >> 2;
  const int ns = (tid & 3) * 16;
  const int nr = tid >> 2;
  const int cs = (tid & 3) * 16;
  float vv[16];
#pragma unroll
  for (int i = 0; i < 16; i++) vv[i] = 0.f;
  for (int t = 0; t < 4; ++t) {
    const float* xp = x + ((size_t)((t * 8 + b) * 512 + c0 + cl)) * 1024 + n0 + ns;
#pragma unroll
    for (int q = 0; q < 4; ++q) {
      f4 xv = *(const f4*)(xp + q * 4);
#pragma unroll
      for (int j = 0; j < 4; ++j) {
        int i = q * 4 + j;
        float v2 = vv[i] + (xv[j] - vv[i]) * 0.5f;   // v + (x-v)/tau
        int spk = (v2 - 1.0f >= 0.0f);
        st[(ns + i) * 80 + cl] = spk ? (u16)0x3C00 : (u16)0;   // fp16 one
        vv[i] = spk ? 0.0f : v2;
      }
    }
    __syncthreads();
    u16* gp = sT + ((size_t)((t * 8 + b) * 1024 + n0 + nr)) * 512 + c0 + cs;
    *(sh8*)(gp) = *(const sh8*)&st[nr * 80 + cs];
    *(sh8*)(gp + 8) = *(const sh8*)&st[nr * 80 + cs + 8];
    __syncthreads();
  }
}

// ---------------------------------------------------------------------------
// Kernel 3: stacked QKV GEMM (fp16 planes folded into K'=1024) + BN + LIF.
// BM=192 BN=256 BK=64, 512 threads (2Mx4N waves, 96x64/wave).
// Counted-vmcnt pipeline: A double-buffered (L2-resident weights, depth 1),
// B triple-buffered (streamed spikes, depth 2). Boundary wait = vmcnt(4),
// never 0 in steady state. LDS 144KB, 1 block/CU, grid 256 = 1/CU.
// ---------------------------------------------------------------------------
__global__ __launch_bounds__(512, 2) void qkv_gemm(
    const u16* __restrict__ w2,      // [1536][1024]
    const u16* __restrict__ sT,      // [t][b][n][512]
    const float* __restrict__ inv4, const float* __restrict__ add4,
    u16* __restrict__ qs, u16* __restrict__ ks, u16* __restrict__ vs) {
  #pragma clang fp contract(off)
  __shared__ u16 lA[2][192 * 64];   // 2 x 24KB
  __shared__ u16 lB[3][256 * 64];   // 3 x 32KB
  const int tid = threadIdx.x;
  const int bid = blockIdx.x;               // 256 blocks
  const int orig = (bid & 7) * 32 + (bid >> 3);   // XCD-chunked (256%8==0)
  const int mI = orig & 7;
  const int nI = (orig >> 3) & 3;
  const int b  = orig >> 5;
  const int m0 = mI * 192;
  const int n0 = nI * 256;
  const int wid = tid >> 6, lane = tid & 63;
  const int l15 = lane & 15, l4 = lane >> 4;
  const int wm = wid >> 2, wn = wid & 3;    // 2M x 4N
  // staging: thread -> (row = tid>>3 within 64-row chunk, phys slot = tid&7);
  // logical k-slot to fetch = phys ^ (row&7)  [both-sides swizzle]
  const int srow = tid >> 3;
  const int sslot = (tid & 7) ^ (srow & 7);
  int aoff[3];
#pragma unroll
  for (int c = 0; c < 3; ++c)
    aoff[c] = (m0 + c * 64 + srow) * 1024 + sslot * 8;
  int boff[4];
#pragma unroll
  for (int c = 0; c < 4; ++c)
    boff[c] = (n0 + c * 64 + srow) * 512 + sslot * 8;

  auto stA = [&](int ii2) {                  // -> lA[ii2 & 1]
    int k0 = (ii2 & 15) * 64;
    u16* d = &lA[ii2 & 1][0];
#pragma unroll
    for (int c = 0; c < 3; ++c)
      aload16(w2 + (size_t)aoff[c] + k0, d + c * 4096 + tid * 8);
  };
  auto stB = [&](int ii2) {                  // -> lB[ii2 % 3]
    int bk0 = (ii2 & 7) * 64;                // k0 mod 512 (planes duplicate B)
    int tt = ii2 >> 4;
    const u16* bb = sT + (size_t)tt * 4194304 + (size_t)b * 524288;
    u16* d = &lB[ii2 % 3][0];
#pragma unroll
    for (int c = 0; c < 4; ++c)
      aload16(bb + (size_t)boff[c] + bk0, d + c * 4096 + tid * 8);
  };

  const f4 fz = {0.f, 0.f, 0.f, 0.f};
  f4 acc[6][4];
  f4 vst[6][4];
#pragma unroll
  for (int i = 0; i < 6; i++)
#pragma unroll
    for (int j = 0; j < 4; j++) vst[i][j] = fz;

  // prologue: tile0 (A,B) + tile1 (B). Steady state: tile i issues A(i+1),B(i+2).
  stA(0); stB(0); stB(1);
  asm volatile("s_waitcnt vmcnt(4)" ::: "memory");   // A(0),B(0) done; B(1) in flight
  __builtin_amdgcn_s_barrier();
  __builtin_amdgcn_sched_barrier(0);

  for (int t = 0; t < 4; ++t) {
#pragma unroll
    for (int i = 0; i < 6; i++)
#pragma unroll
      for (int j = 0; j < 4; j++) acc[i][j] = fz;

    for (int i = 0; i < 16; ++i) {
      const int ii = t * 16 + i;
      const u16* bufA = &lA[ii & 1][0];
      const u16* bufB = &lB[ii % 3][0];
      // ---- phase 0: read A(mh0)+B(nh0); issue next stages (counted pipeline)
      hf8 A0[3][2], Bq[2][2];
#pragma unroll
      for (int mf = 0; mf < 3; ++mf)
#pragma unroll
        for (int kk = 0; kk < 2; ++kk) {
          int lr = wm * 96 + mf * 16 + l15;
          A0[mf][kk] = *(const hf8*)&bufA[lr * 64 + (((kk * 4 + l4) ^ (l15 & 7)) * 8)];
        }
#pragma unroll
      for (int nf = 0; nf < 2; ++nf)
#pragma unroll
        for (int kk = 0; kk < 2; ++kk) {
          int lr = wn * 64 + nf * 16 + l15;
          Bq[nf][kk] = *(const hf8*)&bufB[lr * 64 + (((kk * 4 + l4) ^ (l15 & 7)) * 8)];
        }
      if (ii < 63) stA(ii + 1);    // overwrites lA[(ii+1)&1], last read tile ii-1
      if (ii < 62) stB(ii + 2);    // overwrites lB[(ii+2)%3], last read tile ii-1
      pbar();
      QUAD12(A0, Bq, 0, 0);
      // ---- phase 1: read B(nh1)
      hf8 B1[2][2];
#pragma unroll
      for (int nf = 0; nf < 2; ++nf)
#pragma unroll
        for (int kk = 0; kk < 2; ++kk) {
          int lr = wn * 64 + (2 + nf) * 16 + l15;
          B1[nf][kk] = *(const hf8*)&bufB[lr * 64 + (((kk * 4 + l4) ^ (l15 & 7)) * 8)];
        }
      pbar();
      QUAD12(A0, B1, 0, 1);
      // ---- phase 2: read A(mh1)
      hf8 A1[3][2];
#pragma unroll
      for (int mf = 0; mf < 3; ++mf)
#pragma unroll
        for (int kk = 0; kk < 2; ++kk) {
          int lr = wm * 96 + (3 + mf) * 16 + l15;
          A1[mf][kk] = *(const hf8*)&bufA[lr * 64 + (((kk * 4 + l4) ^ (l15 & 7)) * 8)];
        }
      pbar();
      QUAD12(A1, B1, 1, 1);
      // ---- phase 3: re-read B(nh0)
#pragma unroll
      for (int nf = 0; nf < 2; ++nf)
#pragma unroll
        for (int kk = 0; kk < 2; ++kk) {
          int lr = wn * 64 + nf * 16 + l15;
          Bq[nf][kk] = *(const hf8*)&bufB[lr * 64 + (((kk * 4 + l4) ^ (l15 & 7)) * 8)];
        }
      pbar();
      QUAD12(A1, Bq, 1, 0);
      // ---- boundary: counted wait — drain A(ii+1)+B(ii+1); keep B(ii+2) in flight
      if (ii < 62) {
        asm volatile("s_waitcnt vmcnt(4)" ::: "memory");
      } else {
        asm volatile("s_waitcnt vmcnt(0)" ::: "memory");
      }
      __builtin_amdgcn_s_barrier();
      __builtin_amdgcn_sched_barrier(0);
    }
    // epilogue: BN + LIF + spike store (bf16 spikes)
#pragma unroll
    for (int mf = 0; mf < 6; ++mf) {
      int f0 = m0 + wm * 96 + mf * 16;       // 16-aligned; never crosses 512
      int br = f0 >> 9;
      u16* dst = br == 0 ? qs : (br == 1 ? ks : vs);
      int ocb = f0 & 511;
#pragma unroll
      for (int r = 0; r < 4; ++r) {
        int oc = ocb + l4 * 4 + r;
        float iv = inv4[br * 512 + oc];
        float ad = add4[br * 512 + oc];
        size_t rowbase = ((size_t)((t * 8 + b) * 512 + oc)) * 1024 + n0;
#pragma unroll
        for (int nf = 0; nf < 4; ++nf) {
          float z = acc[mf][nf][r] * iv + ad;
          float v2 = vst[mf][nf][r];
          v2 = v2 + (z - v2) * 0.5f;
          int spk = (v2 - 1.0f >= 0.0f);
          vst[mf][nf][r] = spk ? 0.0f : v2;
          dst[rowbase + wn * 64 + nf * 16 + l15] = spk ? (u16)0x3F80 : (u16)0;
        }
      }
    }
  }
}

// ---------------------------------------------------------------------------
// Kernel 4: kvT[e][d] = sum_n v[e,n]*k[d,n], per (t,b,h), single pass K=1024.
// Exact integers (<=1024) in fp32 MFMA chain. kvp[tbh][64][64].
// ---------------------------------------------------------------------------
__global__ __launch_bounds__(256) void kv_gemm(const u16* __restrict__ ks,
                                               const u16* __restrict__ vs,
                                               float* __restrict__ kvp) {
  const int tbh = blockIdx.x;  // (t*8+b)*8+h ; 256 blocks
  const int tid = threadIdx.x;
  const int wv = tid >> 6, lane = tid & 63, l15 = lane & 15, l4 = lane >> 4;
  const size_t cb = ((size_t)(tbh >> 3) * 512 + (size_t)(tbh & 7) * 64) * 1024;
  const u16* vbase = vs + cb;
  const u16* kbase = ks + cb;
  const f4 fz = {0.f, 0.f, 0.f, 0.f};
  f4 acc[4];
#pragma unroll
  for (int i = 0; i < 4; i++) acc[i] = fz;
  for (int s = 0; s < 32; ++s) {
    int kk = s * 32 + l4 * 8;
    sh8 av = *(const sh8*)(vbase + (size_t)(wv * 16 + l15) * 1024 + kk);
#pragma unroll
    for (int df = 0; df < 4; ++df) {
      sh8 bk = *(const sh8*)(kbase + (size_t)(df * 16 + l15) * 1024 + kk);
      acc[df] = MFMA16B(av, bk, acc[df]);
    }
  }
  float* out = kvp + (size_t)tbh * 4096;
#pragma unroll
  for (int df = 0; df < 4; ++df)
#pragma unroll
    for (int r = 0; r < 4; ++r)
      out[(wv * 16 + l4 * 4 + r) * 64 + df * 16 + l15] = acc[df][r];
}

// ---------------------------------------------------------------------------
// Kernel 5: att = (kv^T @ q)*0.125 per head, then LIF; exact integer path.
// ---------------------------------------------------------------------------
__global__ __launch_bounds__(256) void att_lif(const u16* __restrict__ qs,
                                               const float* __restrict__ kvp,
                                               u16* __restrict__ aT) {
  #pragma clang fp contract(off)
  __shared__ u16 ldsb[64 * 72 * 2 + 128 * 72];
  u16* lkhi = ldsb;                 // [64 e][72]
  u16* lklo = ldsb + 64 * 72;       // [64 e][72]
  u16* lqT = ldsb + 64 * 72 * 2;    // [128 n][72]
  u16* lsp = ldsb;                  // alias: [128 n][72] spike transpose buf
  const int tid = threadIdx.x;
  const int n0 = blockIdx.x * 128;
  const int b = blockIdx.y >> 3;
  const int h = blockIdx.y & 7;
  const int wv = tid >> 6, lane = tid & 63, l15 = lane & 15, l4 = lane >> 4;
  const int e_s = tid >> 2, ds_ = (tid & 3) * 16;
  const f4 fz = {0.f, 0.f, 0.f, 0.f};
  f4 vst[4][2];
#pragma unroll
  for (int i = 0; i < 4; i++)
#pragma unroll
    for (int j = 0; j < 2; j++) vst[i][j] = fz;

  for (int t = 0; t < 4; ++t) {
    int tb = t * 8 + b;
    int tbh = tb * 8 + h;
    {  // stage kv: split into exact bf16 hi/lo
      const float* base = kvp + (size_t)tbh * 4096 + e_s * 64 + ds_;
#pragma unroll
      for (int q = 0; q < 4; ++q) {
        f4 s4 = *(const f4*)(base + q * 4);
#pragma unroll
        for (int j = 0; j < 4; ++j) {
          float sv = s4[j];
          u16 hb = f2bf(sv);
          float lof = sv - bf2f(hb);
          lkhi[e_s * 72 + ds_ + q * 4 + j] = hb;
          lklo[e_s * 72 + ds_ + q * 4 + j] = f2bf(lof);
        }
      }
    }
    {  // stage q transposed: lqT[n][d]
      const u16* qb = qs + ((size_t)tb * 512 + h * 64) * 1024 + n0;
#pragma unroll
      for (int it = 0; it < 4; ++it) {
        int lin = it * 2048 + tid * 8;
        int d = lin >> 7, j0 = lin & 127;
        sh8 qv = *(const sh8*)(qb + (size_t)d * 1024 + j0);
#pragma unroll
        for (int j = 0; j < 8; ++j) lqT[(j0 + j) * 72 + d] = (u16)qv[j];
      }
    }
    __syncthreads();
    f4 acc[4][2];
#pragma unroll
    for (int i = 0; i < 4; i++)
#pragma unroll
      for (int j = 0; j < 2; j++) acc[i][j] = fz;
#pragma unroll
    for (int ksx = 0; ksx < 2; ++ksx) {
      sh8 bq[2];
#pragma unroll
      for (int nf = 0; nf < 2; ++nf)
        bq[nf] = *(const sh8*)&lqT[(wv * 32 + nf * 16 + l15) * 72 + ksx * 32 + l4 * 8];
#pragma unroll
      for (int mf = 0; mf < 4; ++mf) {
        sh8 ah = *(const sh8*)&lkhi[(mf * 16 + l15) * 72 + ksx * 32 + l4 * 8];
        sh8 al = *(const sh8*)&lklo[(mf * 16 + l15) * 72 + ksx * 32 + l4 * 8];
#pragma unroll
        for (int nf = 0; nf < 2; ++nf) {
          acc[mf][nf] = MFMA16B(ah, bq[nf], acc[mf][nf]);
          acc[mf][nf] = MFMA16B(al, bq[nf], acc[mf][nf]);
        }
      }
    }
    __syncthreads();  // all reads of lkhi/lklo done before alias overwrite
#pragma unroll
    for (int mf = 0; mf < 4; ++mf)
#pragma unroll
      for (int nf = 0; nf < 2; ++nf)
#pragma unroll
        for (int r = 0; r < 4; ++r) {
          float xatt = acc[mf][nf][r] * 0.125f;  // exact
          float v2 = vst[mf][nf][r];
          v2 = v2 + (xatt - v2) * 0.5f;          // exact dyadic
          int spk = (v2 - 1.0f >= 0.0f);
          vst[mf][nf][r] = spk ? 0.0f : v2;
          int e = mf * 16 + l4 * 4 + r;
          int n = wv * 32 + nf * 16 + l15;
          lsp[n * 72 + e] = spk ? (u16)0x3C00 : (u16)0;   // fp16 one
        }
    __syncthreads();
    {  // store a_T rows (c contiguous)
#pragma unroll
      for (int it = 0; it < 2; ++it) {
        int lin = it * 256 + tid;
        int n = lin >> 2, es = (lin & 3) * 16;
        u16* gp = aT + ((size_t)(tb * 1024 + n0 + n)) * 512 + h * 64 + es;
        *(sh8*)gp = *(const sh8*)&lsp[n * 72 + es];
        *(sh8*)(gp + 8) = *(const sh8*)&lsp[n * 72 + es + 8];
      }
    }
    __syncthreads();
  }
}

// ---------------------------------------------------------------------------
// Kernel 6: proj GEMM (2-plane fp16) + bias + BN -> out fp32 (round-3 structure).
// ---------------------------------------------------------------------------
__global__ __launch_bounds__(256, 2) void proj_gemm(
    const u16* __restrict__ w2, const u16* __restrict__ aT,
    const float* __restrict__ inv4, const float* __restrict__ add4,
    const float* __restrict__ pb, float* __restrict__ out) {
  #pragma clang fp contract(off)
  __shared__ u16 lA[2 * 128 * 32];
  __shared__ u16 lB[128 * 32];
  const int tid = threadIdx.x;
  const int m0 = blockIdx.x * 128;
  const int n0 = blockIdx.y * 128;
  const int tb = blockIdx.z;
  const int lane = tid & 63, wv = tid >> 6;
  const int l15 = lane & 15, l4 = lane >> 4;
  const int wm = wv >> 1, wn = wv & 1;
  const int rA = tid >> 2;
  const int kswz = (((tid & 3) ^ ((tid >> 3) & 3)) * 8);
  const int sA = (l4 ^ ((l15 >> 1) & 3)) * 8;

  size_t aoff[4];
#pragma unroll
  for (int c = 0; c < 4; ++c) {
    int rf = c * 64 + rA;
    int sp = rf >> 7, r = rf & 127;
    aoff[c] = (size_t)(sp * 512 + m0 + r) * 512 + kswz;
  }
  size_t boff[2];
#pragma unroll
  for (int c = 0; c < 2; ++c) boff[c] = (size_t)(c * 64 + rA) * 512 + kswz;

  const f4 fz = {0.f, 0.f, 0.f, 0.f};
  f4 acc[4][4];
#pragma unroll
  for (int i = 0; i < 4; i++)
#pragma unroll
    for (int j = 0; j < 4; j++) acc[i][j] = fz;
  const u16* aTt = aT + ((size_t)tb * 1024 + n0) * 512;

  for (int k0 = 0; k0 < 512; k0 += 32) {
#pragma unroll
    for (int c = 0; c < 4; ++c)
      aload16(w2 + aoff[c] + k0, &lA[c * 2048 + tid * 8]);
#pragma unroll
    for (int c = 0; c < 2; ++c)
      aload16(aTt + boff[c] + k0, &lB[c * 2048 + tid * 8]);
    __syncthreads();
    hf8 bfr[4];
#pragma unroll
    for (int nf = 0; nf < 4; ++nf)
      bfr[nf] = *(const hf8*)&lB[(wn * 64 + nf * 16 + l15) * 32 + sA];
#pragma unroll
    for (int sp = 0; sp < 2; ++sp) {
#pragma unroll
      for (int mf = 0; mf < 4; ++mf) {
        hf8 afr = *(const hf8*)&lA[sp * 4096 + (wm * 64 + mf * 16 + l15) * 32 + sA];
#pragma unroll
        for (int nf = 0; nf < 4; ++nf) acc[mf][nf] = MFMA16H(afr, bfr[nf], acc[mf][nf]);
      }
    }
    __syncthreads();
  }
#pragma unroll
  for (int mf = 0; mf < 4; ++mf) {
#pragma unroll
    for (int r = 0; r < 4; ++r) {
      int o = m0 + wm * 64 + mf * 16 + l4 * 4 + r;
      float iv = inv4[3 * 512 + o];
      float ad = add4[3 * 512 + o];
      float bias = pb[o];
      size_t rowbase = ((size_t)(tb * 512 + o)) * 1024 + n0;
#pragma unroll
      for (int nf = 0; nf < 4; ++nf) {
        float z = (acc[mf][nf][r] + bias) * iv + ad;
        out[rowbase + wn * 64 + nf * 16 + l15] = z;
      }
    }
  }
}

// ---------------------------------------------------------------------------
extern "C" void kernel_launch(void* const* d_in, const int* in_sizes, int n_in,
                              void* d_out, int out_size, void* d_ws, size_t ws_size,
                              hipStream_t stream) {
  const float* x = (const float*)d_in[0];
  const float* qw = (const float*)d_in[1];
  const float* kw = (const float*)d_in[6];
  const float* vw = (const float*)d_in[11];
  const float* pw = (const float*)d_in[16];
  const float* pb = (const float*)d_in[21];

  char* p = (char*)d_ws;
  u16* w2qkv = (u16*)p; p += (size_t)1536 * 1024 * 2;      // 3.1 MB
  u16* w2p = (u16*)p;   p += (size_t)2 * 512 * 512 * 2;    // 1.0 MB
  float* inv4 = (float*)p; p += 4 * 512 * 4;
  float* add4 = (float*)p; p += 4 * 512 * 4;
  u16* sT = (u16*)p;    p += (size_t)4 * 8 * 1024 * 512 * 2;  // 33.5 MB (reused as aT)
  u16* qs = (u16*)p;    p += (size_t)4 * 8 * 512 * 1024 * 2;
  u16* ks = (u16*)p;    p += (size_t)4 * 8 * 512 * 1024 * 2;
  u16* vs = (u16*)p;    p += (size_t)4 * 8 * 512 * 1024 * 2;
  float* kvp = (float*)p; p += (size_t)256 * 4096 * 4;        // 4.2 MB
  u16* aT = sT;  // s_T dead after qkv_gemm; reuse region for a_T
  float* out = (float*)d_out;

  prep_weights<<<dim3(2048), dim3(256), 0, stream>>>(qw, kw, vw, pw, w2qkv, w2p);
  for (int s = 0; s < 4; ++s) {
    const float* g  = (const float*)d_in[2 + s * 5];
    const float* be = (const float*)d_in[3 + s * 5];
    const float* mu = (const float*)d_in[4 + s * 5];
    const float* va = (const float*)d_in[5 + s * 5];
    bn_prep<<<dim3(2), dim3(256), 0, stream>>>(g, be, mu, va, inv4 + s * 512, add4 + s * 512);
  }
  lif0<<<dim3(16, 8, 8), dim3(256), 0, stream>>>(x, sT);
  qkv_gemm<<<dim3(256), dim3(512), 0, stream>>>(w2qkv, sT, inv4, add4, qs, ks, vs);
  kv_gemm<<<dim3(256), dim3(256), 0, stream>>>(ks, vs, kvp);
  att_lif<<<dim3(8, 64), dim3(256), 0, stream>>>(qs, kvp, aT);
  proj_gemm<<<dim3(4, 8, 32), dim3(256), 0, stream>>>(w2p, aT, inv4, add4, pb, out);
}

// Round 6
// 247.303 us; speedup vs baseline: 1.0368x; 1.0368x over previous
//
#include <hip/hip_runtime.h>
#include <cstdint>
#include <cstddef>

typedef unsigned short u16;
typedef __attribute__((ext_vector_type(8))) short sh8;       // 8 x 16-bit (4 VGPR)
typedef __attribute__((ext_vector_type(8))) _Float16 hf8;    // 8 fp16 (4 VGPR)
typedef __attribute__((ext_vector_type(4))) float f4;        // 4 f32

#define MFMA16B(a, b, c) __builtin_amdgcn_mfma_f32_16x16x32_bf16((a), (b), (c), 0, 0, 0)
#define MFMA16H(a, b, c) __builtin_amdgcn_mfma_f32_16x16x32_f16((a), (b), (c), 0, 0, 0)

__device__ __forceinline__ u16 f2bf(float f) {
  union { float f; uint32_t u; } v; v.f = f;
  uint32_t u = v.u;
  uint32_t lsb = (u >> 16) & 1u;
  return (u16)((u + 0x7fffu + lsb) >> 16);   // RNE
}
__device__ __forceinline__ float bf2f(u16 h) {
  union { uint32_t u; float f; } v; v.u = ((uint32_t)h) << 16;
  return v.f;
}

// async global->LDS, 16B per lane. LDS dest must be linear in lane order.
__device__ __forceinline__ void aload16(const void* g, void* l) {
  __builtin_amdgcn_global_load_lds(
      (const __attribute__((address_space(1))) uint32_t*)g,
      (__attribute__((address_space(3))) uint32_t*)l, 16, 0, 0);
}

__device__ __forceinline__ void pbar() {            // phase barrier (no drain)
  __builtin_amdgcn_sched_barrier(0);
  __builtin_amdgcn_s_barrier();
  __builtin_amdgcn_sched_barrier(0);
}

// 12 MFMAs: 6 m-frags x 2 n-frags into acc[mf][NB+nf]
#define MFMA12(Af, Bf, NB)                                                    \
  {                                                                           \
    __builtin_amdgcn_s_setprio(1);                                            \
    _Pragma("unroll") for (int nf = 0; nf < 2; ++nf)                          \
      _Pragma("unroll") for (int mf = 0; mf < 6; ++mf)                        \
        acc[mf][(NB) + nf] = MFMA16H(Af[mf], Bf[nf], acc[mf][(NB) + nf]);     \
    __builtin_amdgcn_s_setprio(0);                                            \
  }

// ---------------------------------------------------------------------------
// Kernel 1: split fp32 weights into 2 fp16 planes.
// qkv layout: [1536][1024] rows = (q|k|v), cols 0-511 = h0, 512-1023 = h1.
// proj layout: [sp][512][512].
// ---------------------------------------------------------------------------
__global__ void prep_weights(const float* __restrict__ qw, const float* __restrict__ kw,
                             const float* __restrict__ vw, const float* __restrict__ pw,
                             u16* __restrict__ w2qkv, u16* __restrict__ w2p) {
  #pragma clang fp contract(off)
  int row = blockIdx.x;  // 0..2047
  for (int c = threadIdx.x; c < 512; c += 256) {
    const float* src;
    if (row < 1536) {
      int br = row >> 9;
      src = (br == 0 ? qw : (br == 1 ? kw : vw)) + (size_t)(row & 511) * 512;
    } else {
      src = pw + (size_t)(row - 1536) * 512;
    }
    float w = src[c];
    _Float16 h0 = (_Float16)w;
    float r1 = w - (float)h0;
    _Float16 h1 = (_Float16)r1;
    union { _Float16 h; u16 u; } u0, u1;
    u0.h = h0; u1.h = h1;
    if (row < 1536) {
      w2qkv[(size_t)row * 1024 + c] = u0.u;
      w2qkv[(size_t)row * 1024 + 512 + c] = u1.u;
    } else {
      int m = row - 1536;
      w2p[(size_t)m * 512 + c] = u0.u;
      w2p[(size_t)(512 + m) * 512 + c] = u1.u;
    }
  }
}

__global__ void bn_prep(const float* __restrict__ g, const float* __restrict__ be,
                        const float* __restrict__ mu, const float* __restrict__ va,
                        float* __restrict__ inv, float* __restrict__ add) {
  #pragma clang fp contract(off)
  int i = blockIdx.x * 256 + threadIdx.x;
  if (i < 512) {
    float iv = g[i] / sqrtf(va[i] + 1e-5f);
    inv[i] = iv;
    add[i] = be[i] - mu[i] * iv;
  }
}

// ---------------------------------------------------------------------------
// Kernel 2: LIF over x -> spikes, stored TRANSPOSED sT[t][b][n][c] (fp16: 0x3C00).
// ---------------------------------------------------------------------------
__global__ __launch_bounds__(256) void lif0(const float* __restrict__ x, u16* __restrict__ sT) {
  #pragma clang fp contract(off)
  __shared__ u16 st[64 * 80];   // [n][c] padded
  const int tid = threadIdx.x;
  const int n0 = blockIdx.x * 64;
  const int c0 = blockIdx.y * 64;
  const int b = blockIdx.z;
  const int cl = tid >> 2;
  const int ns = (tid & 3) * 16;
  const int nr = tid >> 2;
  const int cs = (tid & 3) * 16;
  float vv[16];
#pragma unroll
  for (int i = 0; i < 16; i++) vv[i] = 0.f;
  for (int t = 0; t < 4; ++t) {
    const float* xp = x + ((size_t)((t * 8 + b) * 512 + c0 + cl)) * 1024 + n0 + ns;
#pragma unroll
    for (int q = 0; q < 4; ++q) {
      f4 xv = *(const f4*)(xp + q * 4);
#pragma unroll
      for (int j = 0; j < 4; ++j) {
        int i = q * 4 + j;
        float v2 = vv[i] + (xv[j] - vv[i]) * 0.5f;   // v + (x-v)/tau
        int spk = (v2 - 1.0f >= 0.0f);
        st[(ns + i) * 80 + cl] = spk ? (u16)0x3C00 : (u16)0;   // fp16 one
        vv[i] = spk ? 0.0f : v2;
      }
    }
    __syncthreads();
    u16* gp = sT + ((size_t)((t * 8 + b) * 1024 + n0 + nr)) * 512 + c0 + cs;
    *(sh8*)(gp) = *(const sh8*)&st[nr * 80 + cs];
    *(sh8*)(gp + 8) = *(const sh8*)&st[nr * 80 + cs + 8];
    __syncthreads();
  }
}

// ---------------------------------------------------------------------------
// Kernel 3: stacked QKV GEMM + BN + LIF. BM=192 BN=256, 512 thr (2Mx4N waves).
// Plane-shared staging: A tile [192][64] = h0|h1 (BK=32/plane, dbuf 2x24KB);
// B tile [256][64] = two K-subtiles, staged once per tile-PAIR (3 bufs x32KB).
// R4 phase discipline: 4 phases + boundary barrier; even-tile boundary keeps
// the pair-ahead B in flight (vmcnt(4)), odd drains (vmcnt(0)). LDS 144KB.
// ---------------------------------------------------------------------------
__global__ __launch_bounds__(512, 2) void qkv_gemm(
    const u16* __restrict__ w2,      // [1536][1024]  (h0 | h1)
    const u16* __restrict__ sT,      // [t][b][n][512]
    const float* __restrict__ inv4, const float* __restrict__ add4,
    u16* __restrict__ qs, u16* __restrict__ ks, u16* __restrict__ vs) {
  #pragma clang fp contract(off)
  __shared__ u16 lA[2][192 * 64];   // 2 x 24KB : [row][pl*32 + k]
  __shared__ u16 lB[3][256 * 64];   // 3 x 32KB : [row][sub*32 + k]
  const int tid = threadIdx.x;
  const int bid = blockIdx.x;               // 256 blocks
  const int orig = (bid & 7) * 32 + (bid >> 3);   // XCD-chunked (256%8==0)
  const int mI = orig & 7;
  const int nI = (orig >> 3) & 3;
  const int b  = orig >> 5;
  const int m0 = mI * 192;
  const int n0 = nI * 256;
  const int wid = tid >> 6, lane = tid & 63;
  const int l15 = lane & 15, l4 = lane >> 4;
  const int wm = wid >> 2, wn = wid & 3;    // 2M x 4N
  const int swz = l15 & 7;                  // read-side XOR
  // staging: thread -> (row = tid>>3 within 64-row chunk, phys slot = tid&7);
  // logical slot to fetch = phys ^ (row&7)  [both-sides swizzle, 8 slots/row]
  const int srow = tid >> 3;
  const int ss = (tid & 7) ^ (srow & 7);
  int aoff[3];   // A slot ss -> plane ss>>2, k-off (ss&3)*8
#pragma unroll
  for (int c = 0; c < 3; ++c)
    aoff[c] = (m0 + c * 64 + srow) * 1024 + (ss >> 2) * 512 + (ss & 3) * 8;
  int boff[4];   // B slot ss -> subtile ss>>2 (k +32), k-off (ss&3)*8
#pragma unroll
  for (int c = 0; c < 4; ++c)
    boff[c] = (n0 + c * 64 + srow) * 512 + (ss >> 2) * 32 + (ss & 3) * 8;

  auto stA = [&](int ii) {                   // tile ii -> lA[ii&1]
    int k0 = (ii & 15) * 32;
    u16* d = &lA[ii & 1][0];
#pragma unroll
    for (int c = 0; c < 3; ++c)
      aload16(w2 + (size_t)(aoff[c] + k0), d + c * 4096 + tid * 8);
  };
  auto stB = [&](int P) {                    // pair P -> lB[P%3]
    int k0 = (P & 7) * 64;
    const u16* bb = sT + (size_t)(P >> 3) * 4194304 + (size_t)b * 524288;
    u16* d = &lB[P % 3][0];
#pragma unroll
    for (int c = 0; c < 4; ++c)
      aload16(bb + (size_t)(boff[c] + k0), d + c * 4096 + tid * 8);
  };

  const f4 fz = {0.f, 0.f, 0.f, 0.f};
  f4 acc[6][4];
  f4 vst[6][4];
#pragma unroll
  for (int i = 0; i < 6; i++)
#pragma unroll
    for (int j = 0; j < 4; j++) vst[i][j] = fz;

  // prologue: A(0), B(pair0), B(pair1)
  stA(0); stB(0); stB(1);
  asm volatile("s_waitcnt vmcnt(4)" ::: "memory");   // A(0)+B(0) done; B(1) flies
  __builtin_amdgcn_s_barrier();
  __builtin_amdgcn_sched_barrier(0);

  for (int t = 0; t < 4; ++t) {
#pragma unroll
    for (int i = 0; i < 6; i++)
#pragma unroll
      for (int j = 0; j < 4; j++) acc[i][j] = fz;

    for (int i = 0; i < 16; ++i) {
      const int ii = t * 16 + i;
      const int P = ii >> 1;
      const u16* bufA = &lA[ii & 1][0];
      const u16* bufB = &lB[P % 3][0];
      const int sb = (ii & 1) * 4;           // B slot base for this subtile
      const bool issueB = ((ii & 1) == 0) && (P + 2 < 32);
      // ---- phase 0: A-h0 frags + B nf0,1; issue prefetches
      hf8 A0[6], Bq[2];
#pragma unroll
      for (int mf = 0; mf < 6; ++mf) {
        int r = wm * 96 + mf * 16 + l15;
        A0[mf] = *(const hf8*)&bufA[r * 64 + ((l4 ^ swz) * 8)];
      }
#pragma unroll
      for (int nf = 0; nf < 2; ++nf) {
        int r = wn * 64 + nf * 16 + l15;
        Bq[nf] = *(const hf8*)&bufB[r * 64 + (((sb + l4) ^ swz) * 8)];
      }
      if (ii < 63) stA(ii + 1);
      if (issueB) stB(P + 2);
      pbar();
      MFMA12(A0, Bq, 0);
      // ---- phase 1: B nf2,3
      hf8 B1[2];
#pragma unroll
      for (int nf = 0; nf < 2; ++nf) {
        int r = wn * 64 + (2 + nf) * 16 + l15;
        B1[nf] = *(const hf8*)&bufB[r * 64 + (((sb + l4) ^ swz) * 8)];
      }
      pbar();
      MFMA12(A0, B1, 2);
      // ---- phase 2: A-h1 frags
      hf8 A1[6];
#pragma unroll
      for (int mf = 0; mf < 6; ++mf) {
        int r = wm * 96 + mf * 16 + l15;
        A1[mf] = *(const hf8*)&bufA[r * 64 + (((4 + l4) ^ swz) * 8)];
      }
      pbar();
      MFMA12(A1, B1, 2);
      // ---- phase 3: B nf0,1 re-read
#pragma unroll
      for (int nf = 0; nf < 2; ++nf) {
        int r = wn * 64 + nf * 16 + l15;
        Bq[nf] = *(const hf8*)&bufB[r * 64 + (((sb + l4) ^ swz) * 8)];
      }
      pbar();
      MFMA12(A1, Bq, 0);
      // ---- boundary: even keeps pair-ahead B in flight; odd drains all
      if (((ii & 1) == 0) && issueB) {
        asm volatile("s_waitcnt vmcnt(4)" ::: "memory");
      } else {
        asm volatile("s_waitcnt vmcnt(0)" ::: "memory");
      }
      __builtin_amdgcn_s_barrier();
      __builtin_amdgcn_sched_barrier(0);
    }
    // epilogue: BN + LIF + spike store (bf16 spikes)
#pragma unroll
    for (int mf = 0; mf < 6; ++mf) {
      int f0 = m0 + wm * 96 + mf * 16;       // 16-aligned; never crosses 512
      int br = f0 >> 9;
      u16* dst = br == 0 ? qs : (br == 1 ? ks : vs);
      int ocb = f0 & 511;
#pragma unroll
      for (int r = 0; r < 4; ++r) {
        int oc = ocb + l4 * 4 + r;
        float iv = inv4[br * 512 + oc];
        float ad = add4[br * 512 + oc];
        size_t rowbase = ((size_t)((t * 8 + b) * 512 + oc)) * 1024 + n0;
#pragma unroll
        for (int nf = 0; nf < 4; ++nf) {
          float z = acc[mf][nf][r] * iv + ad;
          float v2 = vst[mf][nf][r];
          v2 = v2 + (z - v2) * 0.5f;
          int spk = (v2 - 1.0f >= 0.0f);
          vst[mf][nf][r] = spk ? 0.0f : v2;
          dst[rowbase + wn * 64 + nf * 16 + l15] = spk ? (u16)0x3F80 : (u16)0;
        }
      }
    }
  }
}

// ---------------------------------------------------------------------------
// Kernel 4: kvT[e][d] = sum_n v[e,n]*k[d,n], per (t,b,h), single pass K=1024.
// ---------------------------------------------------------------------------
__global__ __launch_bounds__(256) void kv_gemm(const u16* __restrict__ ks,
                                               const u16* __restrict__ vs,
                                               float* __restrict__ kvp) {
  const int tbh = blockIdx.x;  // (t*8+b)*8+h ; 256 blocks
  const int tid = threadIdx.x;
  const int wv = tid >> 6, lane = tid & 63, l15 = lane & 15, l4 = lane >> 4;
  const size_t cb = ((size_t)(tbh >> 3) * 512 + (size_t)(tbh & 7) * 64) * 1024;
  const u16* vbase = vs + cb;
  const u16* kbase = ks + cb;
  const f4 fz = {0.f, 0.f, 0.f, 0.f};
  f4 acc[4];
#pragma unroll
  for (int i = 0; i < 4; i++) acc[i] = fz;
  for (int s = 0; s < 32; ++s) {
    int kk = s * 32 + l4 * 8;
    sh8 av = *(const sh8*)(vbase + (size_t)(wv * 16 + l15) * 1024 + kk);
#pragma unroll
    for (int df = 0; df < 4; ++df) {
      sh8 bk = *(const sh8*)(kbase + (size_t)(df * 16 + l15) * 1024 + kk);
      acc[df] = MFMA16B(av, bk, acc[df]);
    }
  }
  float* out = kvp + (size_t)tbh * 4096;
#pragma unroll
  for (int df = 0; df < 4; ++df)
#pragma unroll
    for (int r = 0; r < 4; ++r)
      out[(wv * 16 + l4 * 4 + r) * 64 + df * 16 + l15] = acc[df][r];
}

// ---------------------------------------------------------------------------
// Kernel 5: att = (kv^T @ q)*0.125 per head, then LIF; exact integer path.
// ---------------------------------------------------------------------------
__global__ __launch_bounds__(256) void att_lif(const u16* __restrict__ qs,
                                               const float* __restrict__ kvp,
                                               u16* __restrict__ aT) {
  #pragma clang fp contract(off)
  __shared__ u16 ldsb[64 * 72 * 2 + 128 * 72];
  u16* lkhi = ldsb;                 // [64 e][72]
  u16* lklo = ldsb + 64 * 72;       // [64 e][72]
  u16* lqT = ldsb + 64 * 72 * 2;    // [128 n][72]
  u16* lsp = ldsb;                  // alias: [128 n][72] spike transpose buf
  const int tid = threadIdx.x;
  const int n0 = blockIdx.x * 128;
  const int b = blockIdx.y >> 3;
  const int h = blockIdx.y & 7;
  const int wv = tid >> 6, lane = tid & 63, l15 = lane & 15, l4 = lane >> 4;
  const int e_s = tid >> 2, ds_ = (tid & 3) * 16;
  const f4 fz = {0.f, 0.f, 0.f, 0.f};
  f4 vst[4][2];
#pragma unroll
  for (int i = 0; i < 4; i++)
#pragma unroll
    for (int j = 0; j < 2; j++) vst[i][j] = fz;

  for (int t = 0; t < 4; ++t) {
    int tb = t * 8 + b;
    int tbh = tb * 8 + h;
    {  // stage kv: split into exact bf16 hi/lo
      const float* base = kvp + (size_t)tbh * 4096 + e_s * 64 + ds_;
#pragma unroll
      for (int q = 0; q < 4; ++q) {
        f4 s4 = *(const f4*)(base + q * 4);
#pragma unroll
        for (int j = 0; j < 4; ++j) {
          float sv = s4[j];
          u16 hb = f2bf(sv);
          float lof = sv - bf2f(hb);
          lkhi[e_s * 72 + ds_ + q * 4 + j] = hb;
          lklo[e_s * 72 + ds_ + q * 4 + j] = f2bf(lof);
        }
      }
    }
    {  // stage q transposed: lqT[n][d]
      const u16* qb = qs + ((size_t)tb * 512 + h * 64) * 1024 + n0;
#pragma unroll
      for (int it = 0; it < 4; ++it) {
        int lin = it * 2048 + tid * 8;
        int d = lin >> 7, j0 = lin & 127;
        sh8 qv = *(const sh8*)(qb + (size_t)d * 1024 + j0);
#pragma unroll
        for (int j = 0; j < 8; ++j) lqT[(j0 + j) * 72 + d] = (u16)qv[j];
      }
    }
    __syncthreads();
    f4 acc[4][2];
#pragma unroll
    for (int i = 0; i < 4; i++)
#pragma unroll
      for (int j = 0; j < 2; j++) acc[i][j] = fz;
#pragma unroll
    for (int ksx = 0; ksx < 2; ++ksx) {
      sh8 bq[2];
#pragma unroll
      for (int nf = 0; nf < 2; ++nf)
        bq[nf] = *(const sh8*)&lqT[(wv * 32 + nf * 16 + l15) * 72 + ksx * 32 + l4 * 8];
#pragma unroll
      for (int mf = 0; mf < 4; ++mf) {
        sh8 ah = *(const sh8*)&lkhi[(mf * 16 + l15) * 72 + ksx * 32 + l4 * 8];
        sh8 al = *(const sh8*)&lklo[(mf * 16 + l15) * 72 + ksx * 32 + l4 * 8];
#pragma unroll
        for (int nf = 0; nf < 2; ++nf) {
          acc[mf][nf] = MFMA16B(ah, bq[nf], acc[mf][nf]);
          acc[mf][nf] = MFMA16B(al, bq[nf], acc[mf][nf]);
        }
      }
    }
    __syncthreads();  // all reads of lkhi/lklo done before alias overwrite
#pragma unroll
    for (int mf = 0; mf < 4; ++mf)
#pragma unroll
      for (int nf = 0; nf < 2; ++nf)
#pragma unroll
        for (int r = 0; r < 4; ++r) {
          float xatt = acc[mf][nf][r] * 0.125f;  // exact
          float v2 = vst[mf][nf][r];
          v2 = v2 + (xatt - v2) * 0.5f;          // exact dyadic
          int spk = (v2 - 1.0f >= 0.0f);
          vst[mf][nf][r] = spk ? 0.0f : v2;
          int e = mf * 16 + l4 * 4 + r;
          int n = wv * 32 + nf * 16 + l15;
          lsp[n * 72 + e] = spk ? (u16)0x3C00 : (u16)0;   // fp16 one
        }
    __syncthreads();
    {  // store a_T rows (c contiguous)
#pragma unroll
      for (int it = 0; it < 2; ++it) {
        int lin = it * 256 + tid;
        int n = lin >> 2, es = (lin & 3) * 16;
        u16* gp = aT + ((size_t)(tb * 1024 + n0 + n)) * 512 + h * 64 + es;
        *(sh8*)gp = *(const sh8*)&lsp[n * 72 + es];
        *(sh8*)(gp + 8) = *(const sh8*)&lsp[n * 72 + es + 8];
      }
    }
    __syncthreads();
  }
}

// ---------------------------------------------------------------------------
// Kernel 6: proj GEMM (2-plane fp16) + bias + BN -> out fp32 (round-3 structure).
// ---------------------------------------------------------------------------
__global__ __launch_bounds__(256, 2) void proj_gemm(
    const u16* __restrict__ w2, const u16* __restrict__ aT,
    const float* __restrict__ inv4, const float* __restrict__ add4,
    const float* __restrict__ pb, float* __restrict__ out) {
  #pragma clang fp contract(off)
  __shared__ u16 lA[2 * 128 * 32];
  __shared__ u16 lB[128 * 32];
  const int tid = threadIdx.x;
  const int m0 = blockIdx.x * 128;
  const int n0 = blockIdx.y * 128;
  const int tb = blockIdx.z;
  const int lane = tid & 63, wv = tid >> 6;
  const int l15 = lane & 15, l4 = lane >> 4;
  const int wm = wv >> 1, wn = wv & 1;
  const int rA = tid >> 2;
  const int kswz = (((tid & 3) ^ ((tid >> 3) & 3)) * 8);
  const int sA = (l4 ^ ((l15 >> 1) & 3)) * 8;

  size_t aoff[4];
#pragma unroll
  for (int c = 0; c < 4; ++c) {
    int rf = c * 64 + rA;
    int sp = rf >> 7, r = rf & 127;
    aoff[c] = (size_t)(sp * 512 + m0 + r) * 512 + kswz;
  }
  size_t boff[2];
#pragma unroll
  for (int c = 0; c < 2; ++c) boff[c] = (size_t)(c * 64 + rA) * 512 + kswz;

  const f4 fz = {0.f, 0.f, 0.f, 0.f};
  f4 acc[4][4];
#pragma unroll
  for (int i = 0; i < 4; i++)
#pragma unroll
    for (int j = 0; j < 4; j++) acc[i][j] = fz;
  const u16* aTt = aT + ((size_t)tb * 1024 + n0) * 512;

  for (int k0 = 0; k0 < 512; k0 += 32) {
#pragma unroll
    for (int c = 0; c < 4; ++c)
      aload16(w2 + aoff[c] + k0, &lA[c * 2048 + tid * 8]);
#pragma unroll
    for (int c = 0; c < 2; ++c)
      aload16(aTt + boff[c] + k0, &lB[c * 2048 + tid * 8]);
    __syncthreads();
    hf8 bfr[4];
#pragma unroll
    for (int nf = 0; nf < 4; ++nf)
      bfr[nf] = *(const hf8*)&lB[(wn * 64 + nf * 16 + l15) * 32 + sA];
#pragma unroll
    for (int sp = 0; sp < 2; ++sp) {
#pragma unroll
      for (int mf = 0; mf < 4; ++mf) {
        hf8 afr = *(const hf8*)&lA[sp * 4096 + (wm * 64 + mf * 16 + l15) * 32 + sA];
#pragma unroll
        for (int nf = 0; nf < 4; ++nf) acc[mf][nf] = MFMA16H(afr, bfr[nf], acc[mf][nf]);
      }
    }
    __syncthreads();
  }
#pragma unroll
  for (int mf = 0; mf < 4; ++mf) {
#pragma unroll
    for (int r = 0; r < 4; ++r) {
      int o = m0 + wm * 64 + mf * 16 + l4 * 4 + r;
      float iv = inv4[3 * 512 + o];
      float ad = add4[3 * 512 + o];
      float bias = pb[o];
      size_t rowbase = ((size_t)(tb * 512 + o)) * 1024 + n0;
#pragma unroll
      for (int nf = 0; nf < 4; ++nf) {
        float z = (acc[mf][nf][r] + bias) * iv + ad;
        out[rowbase + wn * 64 + nf * 16 + l15] = z;
      }
    }
  }
}

// ---------------------------------------------------------------------------
extern "C" void kernel_launch(void* const* d_in, const int* in_sizes, int n_in,
                              void* d_out, int out_size, void* d_ws, size_t ws_size,
                              hipStream_t stream) {
  const float* x = (const float*)d_in[0];
  const float* qw = (const float*)d_in[1];
  const float* kw = (const float*)d_in[6];
  const float* vw = (const float*)d_in[11];
  const float* pw = (const float*)d_in[16];
  const float* pb = (const float*)d_in[21];

  char* p = (char*)d_ws;
  u16* w2qkv = (u16*)p; p += (size_t)1536 * 1024 * 2;      // 3.1 MB
  u16* w2p = (u16*)p;   p += (size_t)2 * 512 * 512 * 2;    // 1.0 MB
  float* inv4 = (float*)p; p += 4 * 512 * 4;
  float* add4 = (float*)p; p += 4 * 512 * 4;
  u16* sT = (u16*)p;    p += (size_t)4 * 8 * 1024 * 512 * 2;  // 33.5 MB (reused as aT)
  u16* qs = (u16*)p;    p += (size_t)4 * 8 * 512 * 1024 * 2;
  u16* ks = (u16*)p;    p += (size_t)4 * 8 * 512 * 1024 * 2;
  u16* vs = (u16*)p;    p += (size_t)4 * 8 * 512 * 1024 * 2;
  float* kvp = (float*)p; p += (size_t)256 * 4096 * 4;        // 4.2 MB
  u16* aT = sT;  // s_T dead after qkv_gemm; reuse region for a_T
  float* out = (float*)d_out;

  prep_weights<<<dim3(2048), dim3(256), 0, stream>>>(qw, kw, vw, pw, w2qkv, w2p);
  for (int s = 0; s < 4; ++s) {
    const float* g  = (const float*)d_in[2 + s * 5];
    const float* be = (const float*)d_in[3 + s * 5];
    const float* mu = (const float*)d_in[4 + s * 5];
    const float* va = (const float*)d_in[5 + s * 5];
    bn_prep<<<dim3(2), dim3(256), 0, stream>>>(g, be, mu, va, inv4 + s * 512, add4 + s * 512);
  }
  lif0<<<dim3(16, 8, 8), dim3(256), 0, stream>>>(x, sT);
  qkv_gemm<<<dim3(256), dim3(512), 0, stream>>>(w2qkv, sT, inv4, add4, qs, ks, vs);
  kv_gemm<<<dim3(256), dim3(256), 0, stream>>>(ks, vs, kvp);
  att_lif<<<dim3(8, 64), dim3(256), 0, stream>>>(qs, kvp, aT);
  proj_gemm<<<dim3(4, 8, 32), dim3(256), 0, stream>>>(w2p, aT, inv4, add4, pb, out);
}